// Round 5
// baseline (890.245 us; speedup 1.0000x reference)
//
#include <hip/hip_runtime.h>

using u16 = unsigned short;
using f32x4 = __attribute__((ext_vector_type(4))) float;
using s16x8 = __attribute__((ext_vector_type(8))) short;
using u32x4 = __attribute__((ext_vector_type(4))) unsigned int;

// ---- problem constants (T=512, B=64, D=256, H=256) ----
#define TT 512
#define BB 64
#define ALPHA 0.9f
// output element offsets (FP32 elements) in d_out, concatenated return order:
// spikes [513,64,256], preds [512,64,256], probs [512,64,256], v_T [64,256], s_T [64,256]
#define SPIKES_OFF 0L
#define PREDS_OFF  8404992L
#define PROBS_OFF  16793600L
#define VT_OFF     25182208L
#define ST_OFF     25198592L

__device__ __forceinline__ u16 f2bf(float f) {
    union { float f; unsigned int i; } cv; cv.f = f;
    unsigned int x = cv.i;
    return (u16)((x + 0x7FFFu + ((x >> 16) & 1u)) >> 16);   // RNE
}

// ---------------------------------------------------------------------------
// One-time: WT[mat] bf16 [n][k] <- W fp32 [k][n], for W_in / W_rec / W_out.
// 3 blocks x 256 thr; reads coalesced (lane = n), writes 16B/thread chunks.
// ---------------------------------------------------------------------------
__global__ void transpose_w(const float* __restrict__ W_in,
                            const float* __restrict__ W_rec,
                            const float* __restrict__ W_out,
                            u16* __restrict__ WT)
{
    const float* src = (blockIdx.x == 0) ? W_in : (blockIdx.x == 1) ? W_rec : W_out;
    u16* dst = WT + (long)blockIdx.x * 65536;
    const int n = threadIdx.x;
    for (int k0 = 0; k0 < 256; k0 += 8) {
        unsigned int dw[4];
        #pragma unroll
        for (int j = 0; j < 4; ++j) {
            unsigned int lo = f2bf(src[(k0 + 2*j    )*256 + n]);
            unsigned int hi = f2bf(src[(k0 + 2*j + 1)*256 + n]);
            dw[j] = lo | (hi << 16);
        }
        u32x4 val = { dw[0], dw[1], dw[2], dw[3] };
        *(u32x4*)&dst[n*256 + k0] = val;
    }
}

// ---------------------------------------------------------------------------
// GEMM: C[m][n] = sum_k A[m][k] * W[k][n] (+ bias[n]).  A fp32 -> bf16 LDS,
// WT bf16 [n][k] from d_ws -> dwordx4 fragment loads.  C fp32.
// MFMA mapping (HW-verified round 4): mfma(wfrag, xfrag, acc) -> lane holds
// D[m = mbase + (lane&15)][n = nbase + quad*4 + r].
// wg 256 thr = 4 waves; tile M=64, all N=256; wave w -> n in [w*64, w*64+64).
// ---------------------------------------------------------------------------
template <bool ADD_BIAS>
__global__ __launch_bounds__(256, 2)
void gemm_rows(const float* __restrict__ A, const u16* __restrict__ WT,
               const float* __restrict__ bias, float* __restrict__ C)
{
    const int tid  = threadIdx.x;
    const int lane = tid & 63;
    const int wave = tid >> 6;
    const int l15  = lane & 15;
    const int quad = lane >> 4;
    const long mblock = (long)blockIdx.x * 64;

    __shared__ u16 Alds[64][264];   // bf16 tile, +8 pad per row

    // stage A tile: 64 rows x 256 fp32 -> bf16
    #pragma unroll
    for (int i = 0; i < 16; ++i) {
        int q = i*256 + tid;
        int r = q >> 6;
        int c = (q & 63) << 2;
        f32x4 a4 = *(const f32x4*)&A[(mblock + r)*256 + c];
        unsigned int b0 = f2bf(a4[0]), b1 = f2bf(a4[1]);
        unsigned int b2 = f2bf(a4[2]), b3 = f2bf(a4[3]);
        uint2 val; val.x = b0 | (b1 << 16); val.y = b2 | (b3 << 16);
        *(uint2*)&Alds[r][c] = val;
    }

    // W^T fragments via contiguous 16B loads (L2-resident WT)
    s16x8 wfrag[4][8];
    const int nbase = wave * 64;
    #pragma unroll
    for (int nt = 0; nt < 4; ++nt)
        #pragma unroll
        for (int kt = 0; kt < 8; ++kt)
            wfrag[nt][kt] = *(const s16x8*)&WT[(nbase + nt*16 + l15)*256 + kt*32 + quad*8];

    __syncthreads();

    f32x4 acc[4][4] = {};   // [mt][nt]
    #pragma unroll
    for (int kt = 0; kt < 8; ++kt) {
        s16x8 xfrag[4];
        #pragma unroll
        for (int mt = 0; mt < 4; ++mt)
            xfrag[mt] = *(const s16x8*)&Alds[mt*16 + l15][kt*32 + quad*8];
        #pragma unroll
        for (int mt = 0; mt < 4; ++mt)
            #pragma unroll
            for (int nt = 0; nt < 4; ++nt)
                acc[mt][nt] = __builtin_amdgcn_mfma_f32_16x16x32_bf16(
                    wfrag[nt][kt], xfrag[mt], acc[mt][nt], 0, 0, 0);
    }

    #pragma unroll
    for (int mt = 0; mt < 4; ++mt) {
        long m = mblock + mt*16 + l15;
        #pragma unroll
        for (int nt = 0; nt < 4; ++nt) {
            int n = nbase + nt*16 + quad*4;
            f32x4 r = acc[mt][nt];
            if (ADD_BIAS) {
                f32x4 bb = *(const f32x4*)&bias[n];
                r[0] += bb[0]; r[1] += bb[1]; r[2] += bb[2]; r[3] += bb[3];
            }
            *(f32x4*)&C[m*256 + n] = r;
        }
    }
}

// ---------------------------------------------------------------------------
// MFMA recurrence. 4 WGs x 256 thr; WG handles 16 batches [B0, B0+16).
// Per step: v = alpha*v + xin(+bias, pre-folded) + s @ W_rec ; s = sigmoid(v).
// MFMA: mfma(wfrag, sfrag, acc): A_op = W_rec^T rows (n), B_op = s (cols = batch).
// Lane holds D[n = nbase + nt*16 + quad*4 + r][m = lane&15]  (verified mapping)
// -> per (nt): 4 consecutive h for batch l15 -> float4 global I/O, b64 LDS write.
// s ping-pong LDS buffer (bf16): ONE barrier per step.
// ---------------------------------------------------------------------------
__global__ __launch_bounds__(256, 1)
void recurrence_mfma(const float* __restrict__ Xin, const float* __restrict__ spike0,
                     const float* __restrict__ v0, const u16* __restrict__ WTrec,
                     float* __restrict__ out)
{
    const int tid  = threadIdx.x;
    const int lane = tid & 63;
    const int wave = tid >> 6;
    const int l15  = lane & 15;
    const int quad = lane >> 4;
    const int B0   = blockIdx.x * 16;
    const int nbase = wave * 64;
    const int hq = quad * 4;              // h offset within a 16-wide n-tile

    __shared__ u16 s_lds[2][16][264];     // [buf][batch][h], row stride 528B (16-mult)

    // W_rec^T A-fragments, register-resident across all 512 steps:
    // lane: n = nbase + nt*16 + l15, k = kt*32 + quad*8 + j  -> 16B contiguous in WT
    s16x8 wfrag[4][8];
    #pragma unroll
    for (int nt = 0; nt < 4; ++nt)
        #pragma unroll
        for (int kt = 0; kt < 8; ++kt)
            wfrag[nt][kt] = *(const s16x8*)&WTrec[(nbase + nt*16 + l15)*256 + kt*32 + quad*8];

    // init s buffer 0 from spike0; also emit spikes[0]
    #pragma unroll
    for (int i = 0; i < 16; ++i) {
        int idx = i*256 + tid;
        int m = idx >> 8, h = idx & 255;
        float s0v = spike0[(B0 + m)*256 + h];
        out[SPIKES_OFF + (B0 + m)*256 + h] = s0v;
        s_lds[0][m][h] = f2bf(s0v);
    }

    // v state + first xin (bias already folded into Xin by gemm1)
    f32x4 v[4], xin_c[4];
    #pragma unroll
    for (int nt = 0; nt < 4; ++nt) {
        const int h = nbase + nt*16 + hq;
        v[nt]     = *(const f32x4*)&v0[(B0 + l15)*256 + h];
        xin_c[nt] = *(const f32x4*)&Xin[(long)(B0 + l15)*256 + h];
    }

    __syncthreads();

    for (int t = 0; t < TT; ++t) {
        const int rb = t & 1, wb = rb ^ 1;

        // prefetch next step's xin early (hides L2/L3 latency behind MFMA+sigmoid)
        f32x4 xin_n[4];
        const int tn = (t + 1 < TT) ? t + 1 : TT - 1;
        const long rowN = (long)(tn*BB + B0 + l15) * 256;
        #pragma unroll
        for (int nt = 0; nt < 4; ++nt)
            xin_n[nt] = *(const f32x4*)&Xin[rowN + nbase + nt*16 + hq];

        // s B-fragments: lane: batch = l15, k = kt*32 + quad*8 + j
        s16x8 sfrag[8];
        #pragma unroll
        for (int kt = 0; kt < 8; ++kt)
            sfrag[kt] = *(const s16x8*)&s_lds[rb][l15][kt*32 + quad*8];

        // acc = alpha*v + xin, then accumulate s @ W_rec via MFMA
        f32x4 acc[4];
        #pragma unroll
        for (int nt = 0; nt < 4; ++nt)
            #pragma unroll
            for (int c = 0; c < 4; ++c)
                acc[nt][c] = fmaf(ALPHA, v[nt][c], xin_c[nt][c]);
        #pragma unroll
        for (int kt = 0; kt < 8; ++kt)
            #pragma unroll
            for (int nt = 0; nt < 4; ++nt)
                acc[nt] = __builtin_amdgcn_mfma_f32_16x16x32_bf16(
                    wfrag[nt][kt], sfrag[kt], acc[nt], 0, 0, 0);

        // sigmoid, state update, outputs
        const long orow = (long)(t*BB + B0 + l15) * 256;
        #pragma unroll
        for (int nt = 0; nt < 4; ++nt) {
            const int h = nbase + nt*16 + hq;
            f32x4 p;
            #pragma unroll
            for (int c = 0; c < 4; ++c)
                p[c] = __builtin_amdgcn_rcpf(1.0f + __expf(-acc[nt][c]));
            v[nt] = acc[nt];
            // s -> LDS (bf16 x4 = one b64 write)
            uint2 sw;
            sw.x = (unsigned int)f2bf(p[0]) | ((unsigned int)f2bf(p[1]) << 16);
            sw.y = (unsigned int)f2bf(p[2]) | ((unsigned int)f2bf(p[3]) << 16);
            *(uint2*)&s_lds[wb][l15][h] = sw;
            // spikes[t+1] and probs[t] (spike == prob), fp32
            *(f32x4*)&out[SPIKES_OFF + orow + 16384 + h] = p;
            *(f32x4*)&out[PROBS_OFF  + orow         + h] = p;
            if (t == TT - 1)
                *(f32x4*)&out[ST_OFF + (B0 + l15)*256 + h] = p;   // s_T = spikes[T]
            xin_c[nt] = xin_n[nt];
        }
        __syncthreads();   // writes to buf[wb] visible; buf[rb] safe to rewrite at t+1
    }

    #pragma unroll
    for (int nt = 0; nt < 4; ++nt)
        *(f32x4*)&out[VT_OFF + (B0 + l15)*256 + nbase + nt*16 + hq] = v[nt];
}

// ---------------------------------------------------------------------------
extern "C" void kernel_launch(void* const* d_in, const int* in_sizes, int n_in,
                              void* d_out, int out_size, void* d_ws, size_t ws_size,
                              hipStream_t stream) {
    const float* inputs = (const float*)d_in[0];   // [512,64,256]
    const float* spike0 = (const float*)d_in[1];   // [64,256]
    const float* v0     = (const float*)d_in[2];   // [64,256]
    const float* W_in   = (const float*)d_in[3];   // [256,256]
    const float* W_rec  = (const float*)d_in[4];   // [256,256]
    const float* W_out  = (const float*)d_in[5];   // [256,256]
    const float* bvec   = (const float*)d_in[6];   // [256]
    float* out = (float*)d_out;

    // d_ws: 3 transposed bf16 weight matrices, 384 KB total.
    u16* WT = (u16*)d_ws;                 // [3][256][256] bf16
    u16* WTin  = WT;
    u16* WTrec = WT + 65536;
    u16* WTout = WT + 131072;

    // Xin (fp32 [32768,256]) staged in the preds output region; overwritten by
    // gemm2 after the recurrence consumes it.
    float* Xin = out + PREDS_OFF;

    transpose_w<<<3, 256, 0, stream>>>(W_in, W_rec, W_out, WT);
    // Xin[t*64+b][h] = inputs[t,b,:] @ W_in + b   (bias folded here)
    gemm_rows<true><<<512, 256, 0, stream>>>(inputs, WTin, bvec, Xin);
    recurrence_mfma<<<4, 256, 0, stream>>>(Xin, spike0, v0, WTrec, out);
    // preds[t,b,:] = spikes[t+1,b,:] @ W_out   (no bias in reference)
    gemm_rows<false><<<512, 256, 0, stream>>>(out + 16384, WTout, bvec, out + PREDS_OFF);
}

// Round 6
// 858.356 us; speedup vs baseline: 1.0372x; 1.0372x over previous
//
#include <hip/hip_runtime.h>

using u16 = unsigned short;
using f32x4 = __attribute__((ext_vector_type(4))) float;
using s16x8 = __attribute__((ext_vector_type(8))) short;
using u32x4 = __attribute__((ext_vector_type(4))) unsigned int;

// ---- problem constants (T=512, B=64, D=256, H=256) ----
#define TT 512
#define BB 64
#define ALPHA 0.9f
// output element offsets (FP32 elements) in d_out, concatenated return order:
// spikes [513,64,256], preds [512,64,256], probs [512,64,256], v_T [64,256], s_T [64,256]
#define SPIKES_OFF 0L
#define PREDS_OFF  8404992L
#define PROBS_OFF  16793600L
#define VT_OFF     25182208L
#define ST_OFF     25198592L

__device__ __forceinline__ u16 f2bf(float f) {
    union { float f; unsigned int i; } cv; cv.f = f;
    unsigned int x = cv.i;
    return (u16)((x + 0x7FFFu + ((x >> 16) & 1u)) >> 16);   // RNE
}

// LDS-only barrier: waits ds ops, NOT the in-flight global stores/loads.
// __syncthreads() would emit s_waitcnt vmcnt(0) and drain every global store
// + prefetch each step (~1500-2000 cyc/step stall, round-5 counters).
__device__ __forceinline__ void lds_barrier() {
    __asm__ volatile("s_waitcnt lgkmcnt(0)\n\ts_barrier" ::: "memory");
}

// ---------------------------------------------------------------------------
// One-time: WT[mat] bf16 [n][k] <- W fp32 [k][n], for W_in / W_rec / W_out.
// ---------------------------------------------------------------------------
__global__ void transpose_w(const float* __restrict__ W_in,
                            const float* __restrict__ W_rec,
                            const float* __restrict__ W_out,
                            u16* __restrict__ WT)
{
    const float* src = (blockIdx.x == 0) ? W_in : (blockIdx.x == 1) ? W_rec : W_out;
    u16* dst = WT + (long)blockIdx.x * 65536;
    const int n = threadIdx.x;
    for (int k0 = 0; k0 < 256; k0 += 8) {
        unsigned int dw[4];
        #pragma unroll
        for (int j = 0; j < 4; ++j) {
            unsigned int lo = f2bf(src[(k0 + 2*j    )*256 + n]);
            unsigned int hi = f2bf(src[(k0 + 2*j + 1)*256 + n]);
            dw[j] = lo | (hi << 16);
        }
        u32x4 val = { dw[0], dw[1], dw[2], dw[3] };
        *(u32x4*)&dst[n*256 + k0] = val;
    }
}

// ---------------------------------------------------------------------------
// GEMM: C[m][n] = sum_k A[m][k] * W[k][n] (+ bias[n]).  A fp32 -> bf16 LDS,
// WT bf16 [n][k] -> dwordx4 fragment loads.  C fp32.
// mfma(wfrag, xfrag, acc) -> lane holds D[m = mbase+(lane&15)][n = nbase+quad*4+r].
// wg 256 thr = 4 waves; tile M=64, all N=256; wave w -> n in [w*64, w*64+64).
// ---------------------------------------------------------------------------
template <bool ADD_BIAS>
__global__ __launch_bounds__(256, 2)
void gemm_rows(const float* __restrict__ A, const u16* __restrict__ WT,
               const float* __restrict__ bias, float* __restrict__ C)
{
    const int tid  = threadIdx.x;
    const int lane = tid & 63;
    const int wave = tid >> 6;
    const int l15  = lane & 15;
    const int quad = lane >> 4;
    const long mblock = (long)blockIdx.x * 64;

    __shared__ u16 Alds[64][264];   // bf16 tile, +8 pad per row

    #pragma unroll
    for (int i = 0; i < 16; ++i) {
        int q = i*256 + tid;
        int r = q >> 6;
        int c = (q & 63) << 2;
        f32x4 a4 = *(const f32x4*)&A[(mblock + r)*256 + c];
        unsigned int b0 = f2bf(a4[0]), b1 = f2bf(a4[1]);
        unsigned int b2 = f2bf(a4[2]), b3 = f2bf(a4[3]);
        uint2 val; val.x = b0 | (b1 << 16); val.y = b2 | (b3 << 16);
        *(uint2*)&Alds[r][c] = val;
    }

    s16x8 wfrag[4][8];
    const int nbase = wave * 64;
    #pragma unroll
    for (int nt = 0; nt < 4; ++nt)
        #pragma unroll
        for (int kt = 0; kt < 8; ++kt)
            wfrag[nt][kt] = *(const s16x8*)&WT[(nbase + nt*16 + l15)*256 + kt*32 + quad*8];

    __syncthreads();

    f32x4 acc[4][4] = {};   // [mt][nt]
    #pragma unroll
    for (int kt = 0; kt < 8; ++kt) {
        s16x8 xfrag[4];
        #pragma unroll
        for (int mt = 0; mt < 4; ++mt)
            xfrag[mt] = *(const s16x8*)&Alds[mt*16 + l15][kt*32 + quad*8];
        #pragma unroll
        for (int mt = 0; mt < 4; ++mt)
            #pragma unroll
            for (int nt = 0; nt < 4; ++nt)
                acc[mt][nt] = __builtin_amdgcn_mfma_f32_16x16x32_bf16(
                    wfrag[nt][kt], xfrag[mt], acc[mt][nt], 0, 0, 0);
    }

    #pragma unroll
    for (int mt = 0; mt < 4; ++mt) {
        long m = mblock + mt*16 + l15;
        #pragma unroll
        for (int nt = 0; nt < 4; ++nt) {
            int n = nbase + nt*16 + quad*4;
            f32x4 r = acc[mt][nt];
            if (ADD_BIAS) {
                f32x4 bb = *(const f32x4*)&bias[n];
                r[0] += bb[0]; r[1] += bb[1]; r[2] += bb[2]; r[3] += bb[3];
            }
            *(f32x4*)&C[m*256 + n] = r;
        }
    }
}

// ---------------------------------------------------------------------------
// MFMA recurrence. 4 WGs x 256 thr (4 waves); WG = 16 batches [B0, B0+16).
// Per step: v = alpha*v + xin + s @ W_rec ; s = sigmoid(v).
// Lane holds D[n = nbase+nt*16+quad*4+r][batch = lane&15] (HW-verified r4).
// s ping-pong in LDS (bf16), ONE raw lds_barrier per step; global stores are
// never waited on; xin prefetched 2 steps ahead (unroll-by-2 ping-pong regs).
// ---------------------------------------------------------------------------
__global__ __launch_bounds__(256, 1)
void recurrence_mfma(const float* __restrict__ Xin, const float* __restrict__ spike0,
                     const float* __restrict__ v0, const u16* __restrict__ WTrec,
                     float* __restrict__ out)
{
    const int tid  = threadIdx.x;
    const int lane = tid & 63;
    const int wave = tid >> 6;
    const int l15  = lane & 15;
    const int quad = lane >> 4;
    const int B0   = blockIdx.x * 16;
    const int nbase = wave * 64;
    const int hq = quad * 4;

    __shared__ u16 s_lds[2][16][264];     // [buf][batch][h]

    // W_rec^T A-fragments, register-resident for all 512 steps
    s16x8 wfrag[4][8];
    #pragma unroll
    for (int nt = 0; nt < 4; ++nt)
        #pragma unroll
        for (int kt = 0; kt < 8; ++kt)
            wfrag[nt][kt] = *(const s16x8*)&WTrec[(nbase + nt*16 + l15)*256 + kt*32 + quad*8];

    // init s buffer 0 from spike0; emit spikes[0]
    #pragma unroll
    for (int i = 0; i < 16; ++i) {
        int idx = i*256 + tid;
        int m = idx >> 8, h = idx & 255;
        float s0v = spike0[(B0 + m)*256 + h];
        out[SPIKES_OFF + (B0 + m)*256 + h] = s0v;
        s_lds[0][m][h] = f2bf(s0v);
    }

    f32x4 v[4], xinA[4], xinB[4];
    #pragma unroll
    for (int nt = 0; nt < 4; ++nt) {
        const int h = nbase + nt*16 + hq;
        v[nt]    = *(const f32x4*)&v0[(B0 + l15)*256 + h];
        xinA[nt] = *(const f32x4*)&Xin[(long)(0*BB + B0 + l15)*256 + h];  // t=0
        xinB[nt] = *(const f32x4*)&Xin[(long)(1*BB + B0 + l15)*256 + h];  // t=1
    }

    __syncthreads();   // one-time full barrier (covers spike0 LDS init)

    #pragma unroll 1
    for (int t2 = 0; t2 < TT; t2 += 2) {
        // ---------------- even step: t = t2, read buf t2&1=0 pattern --------
        #pragma unroll
        for (int half = 0; half < 2; ++half) {
            const int t  = t2 + half;
            const int rb = t & 1, wb = rb ^ 1;

            // s B-fragments from LDS: lane: batch=l15, k = kt*32+quad*8+j
            s16x8 sfrag[8];
            #pragma unroll
            for (int kt = 0; kt < 8; ++kt)
                sfrag[kt] = *(const s16x8*)&s_lds[rb][l15][kt*32 + quad*8];

            // acc = alpha*v + xin (consume this step's buffer)
            f32x4 acc[4];
            #pragma unroll
            for (int nt = 0; nt < 4; ++nt)
                #pragma unroll
                for (int c = 0; c < 4; ++c)
                    acc[nt][c] = fmaf(ALPHA, v[nt][c],
                                      half == 0 ? xinA[nt][c] : xinB[nt][c]);

            // prefetch xin for t+2 into the buffer just consumed
            {
                const int tp = (t + 2 < TT) ? t + 2 : TT - 1;
                const long rowP = (long)(tp*BB + B0 + l15) * 256;
                #pragma unroll
                for (int nt = 0; nt < 4; ++nt) {
                    f32x4 ld = *(const f32x4*)&Xin[rowP + nbase + nt*16 + hq];
                    if (half == 0) xinA[nt] = ld; else xinB[nt] = ld;
                }
            }

            // accumulate s @ W_rec
            #pragma unroll
            for (int kt = 0; kt < 8; ++kt)
                #pragma unroll
                for (int nt = 0; nt < 4; ++nt)
                    acc[nt] = __builtin_amdgcn_mfma_f32_16x16x32_bf16(
                        wfrag[nt][kt], sfrag[kt], acc[nt], 0, 0, 0);

            // sigmoid, state, outputs
            const long orow = (long)(t*BB + B0 + l15) * 256;
            #pragma unroll
            for (int nt = 0; nt < 4; ++nt) {
                const int h = nbase + nt*16 + hq;
                f32x4 p;
                #pragma unroll
                for (int c = 0; c < 4; ++c)
                    p[c] = __builtin_amdgcn_rcpf(1.0f + __expf(-acc[nt][c]));
                v[nt] = acc[nt];
                uint2 sw;
                sw.x = (unsigned int)f2bf(p[0]) | ((unsigned int)f2bf(p[1]) << 16);
                sw.y = (unsigned int)f2bf(p[2]) | ((unsigned int)f2bf(p[3]) << 16);
                *(uint2*)&s_lds[wb][l15][h] = sw;
                *(f32x4*)&out[SPIKES_OFF + orow + 16384 + h] = p;   // spikes[t+1]
                *(f32x4*)&out[PROBS_OFF  + orow         + h] = p;   // probs[t]
                if (t == TT - 1)
                    *(f32x4*)&out[ST_OFF + (B0 + l15)*256 + h] = p; // s_T
            }
            lds_barrier();   // LDS-only: no vmcnt drain of stores/prefetch
        }
    }

    #pragma unroll
    for (int nt = 0; nt < 4; ++nt)
        *(f32x4*)&out[VT_OFF + (B0 + l15)*256 + nbase + nt*16 + hq] = v[nt];
}

// ---------------------------------------------------------------------------
extern "C" void kernel_launch(void* const* d_in, const int* in_sizes, int n_in,
                              void* d_out, int out_size, void* d_ws, size_t ws_size,
                              hipStream_t stream) {
    const float* inputs = (const float*)d_in[0];   // [512,64,256]
    const float* spike0 = (const float*)d_in[1];   // [64,256]
    const float* v0     = (const float*)d_in[2];   // [64,256]
    const float* W_in   = (const float*)d_in[3];   // [256,256]
    const float* W_rec  = (const float*)d_in[4];   // [256,256]
    const float* W_out  = (const float*)d_in[5];   // [256,256]
    const float* bvec   = (const float*)d_in[6];   // [256]
    float* out = (float*)d_out;

    // d_ws: 3 transposed bf16 weight matrices, 384 KB.
    u16* WT = (u16*)d_ws;
    u16* WTin  = WT;
    u16* WTrec = WT + 65536;
    u16* WTout = WT + 131072;

    // Xin (fp32 [32768,256]) staged in the preds output region; overwritten by
    // gemm2 after the recurrence consumes it.
    float* Xin = out + PREDS_OFF;

    transpose_w<<<3, 256, 0, stream>>>(W_in, W_rec, W_out, WT);
    gemm_rows<true><<<512, 256, 0, stream>>>(inputs, WTin, bvec, Xin);
    recurrence_mfma<<<4, 256, 0, stream>>>(Xin, spike0, v0, WTrec, out);
    gemm_rows<false><<<512, 256, 0, stream>>>(out + 16384, WTout, bvec, out + PREDS_OFF);
}